// Round 13
// baseline (430.359 us; speedup 1.0000x reference)
//
#include <hip/hip_runtime.h>

// ---------------------------------------------------------------------------
// VAERNN forward posterior, MI355X bf16-MFMA implementation.
// L=256 B=512 K=128 IN=64 STATE=128 OBS=128, LB = L*B = 131072 rows.
// ---------------------------------------------------------------------------

typedef __attribute__((ext_vector_type(8))) short bf16x8;
typedef __attribute__((ext_vector_type(4))) short bf16x4;
typedef __attribute__((ext_vector_type(4))) float f32x4;

#define LB 131072

__device__ __forceinline__ short f2b(float f) {
  union { float f; unsigned u; } v; v.f = f;
  unsigned r = (v.u + 0x7FFFu + ((v.u >> 16) & 1u)) >> 16;  // RNE
  return (short)r;
}
__device__ __forceinline__ float u2f(unsigned u) {
  union { unsigned u; float f; } v; v.u = u << 16; return v.f;
}
__device__ __forceinline__ float rcpf(float x) { return __builtin_amdgcn_rcpf(x); }
__device__ __forceinline__ float exp2f_(float x) { return __builtin_amdgcn_exp2f(x); }
__device__ __forceinline__ float sigm(float x) { return rcpf(1.f + exp2f_(-1.44269504f * x)); }

// lgkm-only barrier: LDS ordering without draining global loads/stores (T4).
#define LGKM_BAR()                                          \
  asm volatile("s_waitcnt lgkmcnt(0)" ::: "memory");        \
  __builtin_amdgcn_s_barrier();                             \
  __builtin_amdgcn_sched_barrier(0);

// ---------------------------------------------------------------------------
// K0: convert all weight matrices fp32 -> bf16 into workspace (contiguous).
// ---------------------------------------------------------------------------
__global__ __launch_bounds__(256) void k_cvt(
    const float* __restrict__ s0, const float* __restrict__ s1,
    const float* __restrict__ s2, const float* __restrict__ s3,
    const float* __restrict__ s4, const float* __restrict__ s5,
    const float* __restrict__ s6, const float* __restrict__ s7,
    const float* __restrict__ s8, const float* __restrict__ s9,
    short* __restrict__ dst)
{
  int i = blockIdx.x * 256 + threadIdx.x;
  if (i >= 352256) return;
  const float* src; int off;
  if      (i <   8192) { src = s0; off = i; }
  else if (i <  24576) { src = s1; off = i - 8192; }
  else if (i <  40960) { src = s2; off = i - 24576; }
  else if (i <  57344) { src = s3; off = i - 40960; }
  else if (i < 106496) { src = s4; off = i - 57344; }
  else if (i < 155648) { src = s5; off = i - 106496; }
  else if (i < 221184) { src = s6; off = i - 155648; }
  else if (i < 286720) { src = s7; off = i - 221184; }
  else if (i < 319488) { src = s8; off = i - 286720; }
  else                 { src = s9; off = i - 319488; }
  dst[i] = f2b(src[off]);
}

// ---------------------------------------------------------------------------
// K1: u-path: x(64) -> relu fc(128) -> relu fc(128) -> gates(384).
// 512 blocks x 512 thr, grid-stride 8 tiles of 32 rows. ALL weights
// register-resident. T14: next tile's x-loads issued right after b1.
// (R11 version — proven.)
// ---------------------------------------------------------------------------
#define UT 8
__global__ __launch_bounds__(512) void k_upath(
    const float* __restrict__ x, const short* __restrict__ w1, const float* __restrict__ b1,
    const short* __restrict__ w2, const float* __restrict__ b2,
    const short* __restrict__ wih, const float* __restrict__ bih,
    const float* __restrict__ bhh,
    short* __restrict__ gates)
{
  __shared__ short Xb[32][72];
  __shared__ short Tb[32][136];
  __shared__ short Gb[32][392];
  const int tid = threadIdx.x, w = tid >> 6, l = tid & 63;
  const int lr = l & 15, lg = l >> 4;
  const int n1 = w * 16 + lr;   // this lane's layer1/layer2 output column

  bf16x8 wf1[2], wf2[4], wfg[3][4];
  #pragma unroll
  for (int kt = 0; kt < 2; ++kt)
    wf1[kt] = *reinterpret_cast<const bf16x8*>(w1 + (size_t)n1 * 64 + kt * 32 + lg * 8);
  #pragma unroll
  for (int kt = 0; kt < 4; ++kt)
    wf2[kt] = *reinterpret_cast<const bf16x8*>(w2 + (size_t)n1 * 128 + kt * 32 + lg * 8);
  float bgv[3];
  #pragma unroll
  for (int j = 0; j < 3; ++j) {
    const int cg = w * 48 + j * 16 + lr;
    bgv[j] = bih[cg] + (cg < 256 ? bhh[cg] : 0.f);  // fold bhh into r/z gates
    #pragma unroll
    for (int kt = 0; kt < 4; ++kt)
      wfg[j][kt] = *reinterpret_cast<const bf16x8*>(wih + (size_t)cg * 128 + kt * 32 + lg * 8);
  }
  const float b1v = b1[n1], b2v = b2[n1];
  const int srow = tid >> 4, scol4 = (tid & 15) * 4, gcol = (tid & 15) * 24;

  // preload tile-0 stage regs (T14)
  float4 sx = *reinterpret_cast<const float4*>(
      x + ((size_t)blockIdx.x * UT * 32 + srow) * 64 + scol4);

  for (int it = 0; it < UT; ++it) {
    const size_t m0 = ((size_t)blockIdx.x * UT + it) * 32;

    // write staged x tile (32 x 64) as bf16
    {
      bf16x4 p; p[0] = f2b(sx.x); p[1] = f2b(sx.y); p[2] = f2b(sx.z); p[3] = f2b(sx.w);
      *reinterpret_cast<bf16x4*>(&Xb[srow][scol4]) = p;
    }
    LGKM_BAR();  // b1: x staged (also drains prev tile's Gb readback reads)

    // T14: issue next tile's x-load now (clamped; hidden under MFMAs below)
    {
      const size_t mn = ((size_t)blockIdx.x * UT + (it + 1 < UT ? it + 1 : it)) * 32;
      sx = *reinterpret_cast<const float4*>(x + (mn + srow) * 64 + scol4);
    }

    // layer1: K=64 -> 16 cols/wave
    f32x4 a1c[2] = {(f32x4){0.f,0.f,0.f,0.f}, (f32x4){0.f,0.f,0.f,0.f}};
    #pragma unroll
    for (int kt = 0; kt < 2; ++kt) {
      #pragma unroll
      for (int mt = 0; mt < 2; ++mt) {
        bf16x8 af = *reinterpret_cast<const bf16x8*>(&Xb[mt * 16 + lr][kt * 32 + lg * 8]);
        a1c[mt] = __builtin_amdgcn_mfma_f32_16x16x32_bf16(af, wf1[kt], a1c[mt], 0, 0, 0);
      }
    }
    #pragma unroll
    for (int mt = 0; mt < 2; ++mt)
      #pragma unroll
      for (int r = 0; r < 4; ++r) {
        float v = a1c[mt][r] + b1v;
        Tb[mt * 16 + lg * 4 + r][n1] = f2b(v > 0.f ? v : 0.f);
      }
    LGKM_BAR();  // b2: layer1 exchanged

    // layer2: K=128 -> 16 cols/wave; output exchanged via Gb[.][0..127]
    f32x4 a2c[2] = {(f32x4){0.f,0.f,0.f,0.f}, (f32x4){0.f,0.f,0.f,0.f}};
    #pragma unroll
    for (int kt = 0; kt < 4; ++kt) {
      #pragma unroll
      for (int mt = 0; mt < 2; ++mt) {
        bf16x8 af = *reinterpret_cast<const bf16x8*>(&Tb[mt * 16 + lr][kt * 32 + lg * 8]);
        a2c[mt] = __builtin_amdgcn_mfma_f32_16x16x32_bf16(af, wf2[kt], a2c[mt], 0, 0, 0);
      }
    }
    #pragma unroll
    for (int mt = 0; mt < 2; ++mt)
      #pragma unroll
      for (int r = 0; r < 4; ++r) {
        float v = a2c[mt][r] + b2v;
        Gb[mt * 16 + lg * 4 + r][n1] = f2b(v > 0.f ? v : 0.f);
      }
    LGKM_BAR();  // b3: u_embed exchanged

    // gates: read A-frags first (regs), then barrier, then overwrite Gb
    bf16x8 ag[2][4];
    #pragma unroll
    for (int mt = 0; mt < 2; ++mt)
      #pragma unroll
      for (int kt = 0; kt < 4; ++kt)
        ag[mt][kt] = *reinterpret_cast<const bf16x8*>(&Gb[mt * 16 + lr][kt * 32 + lg * 8]);
    LGKM_BAR();  // b4: all u_embed reads done; Gb free for gate outputs

    #pragma unroll
    for (int j = 0; j < 3; ++j) {
      #pragma unroll
      for (int mt = 0; mt < 2; ++mt) {
        f32x4 c = {0.f, 0.f, 0.f, 0.f};
        #pragma unroll
        for (int kt = 0; kt < 4; ++kt)
          c = __builtin_amdgcn_mfma_f32_16x16x32_bf16(ag[mt][kt], wfg[j][kt], c, 0, 0, 0);
        #pragma unroll
        for (int r = 0; r < 4; ++r)
          Gb[mt * 16 + lg * 4 + r][w * 48 + j * 16 + lr] = f2b(c[r] + bgv[j]);
      }
    }
    LGKM_BAR();  // b5: gate tile assembled

    // vectorized readback + coalesced global store (row: 16 lanes x 48B)
    #pragma unroll
    for (int k = 0; k < 3; ++k) {
      bf16x8 vv = *reinterpret_cast<const bf16x8*>(&Gb[srow][gcol + k * 8]);
      *reinterpret_cast<bf16x8*>(gates + (m0 + srow) * 384 + gcol + k * 8) = vv;
    }
    // next tile's b1 drains these LDS reads before Gb is rewritten
  }
}

// ---------------------------------------------------------------------------
// K2: fused GRU scan + x-path (heterogeneous blocks). (R11 structure.)
// LDS padded past 80 KB -> 1 block/CU. Blocks 0..127: GRU, sequential 4-deep
// MFMA chains, permlane full redistribution, setprio(1).
// NEW (R13): strength-reduced pointers — gate-prefetch and hseq addresses
// advance by constant byte strides per step instead of recomputing 64-bit
// muls. The 2-step-ahead prefetch runs past the gates region by <=0.8 MB into
// the (valid, unread) output buffer — loads only, values never consumed.
// Blocks 128..639: x-path embedding.
// ---------------------------------------------------------------------------
__global__ __launch_bounds__(512) void k_grux(
    const short* __restrict__ gates, const short* __restrict__ whh,
    const float* __restrict__ bhh, float* __restrict__ hseq,
    const float* __restrict__ obs, const short* __restrict__ xw1,
    const float* __restrict__ xb1, const short* __restrict__ xw2,
    const float* __restrict__ xb2, float* __restrict__ xe)
{
  __shared__ short smem_[41088];   // 82176 B > 80 KB -> 1 block/CU (exclusivity)
  const int tid = threadIdx.x, w = tid >> 6, l = tid & 63;
  const int lr = l & 15, lg = l >> 4;

  if (blockIdx.x < 128) {
    // ---------------- GRU path ----------------
    short (*hb)[16][136] = reinterpret_cast<short (*)[16][136]>(smem_);
    const int m0 = blockIdx.x * 4;
    const int c = w * 16 + lr;   // this lane's h/gate column (0..127)
    const int row = lg;          // this lane's batch row within tile (0..3)
    const size_t gr = m0 + row;  // global batch row

    bf16x8 bfr[3][4];
    #pragma unroll
    for (int g = 0; g < 3; ++g)
      #pragma unroll
      for (int kt = 0; kt < 4; ++kt)
        bfr[g][kt] = *reinterpret_cast<const bf16x8*>(whh + (size_t)(g * 128 + c) * 128 + kt * 32 + lg * 8);
    const float bbn = bhh[256 + c];  // only the n-gate bias survives (scaled by r)

    for (int i = tid; i < 2 * 16 * 136; i += 512) smem_[i] = 0;

    float hold = 0.f;

    // strength-reduced pointers:
    //   gate prefetch: 1 pointer per gate at (t=2)-position, += GSTEP/step
    //   hseq store:    1 pointer at t=0 position, += HSTEP/step
    const size_t GSTEP = (size_t)512 * 384;   // shorts per timestep in gates
    const size_t HSTEP = (size_t)512 * 128;   // floats per timestep in hseq
    const short* gp0 = gates + (size_t)2 * GSTEP + gr * 384 + 0 * 128 + c;
    const short* gp1 = gates + (size_t)2 * GSTEP + gr * 384 + 1 * 128 + c;
    const short* gp2 = gates + (size_t)2 * GSTEP + gr * 384 + 2 * 128 + c;
    float* hp = hseq + gr * 128 + c;

    unsigned gA[3], gB[3];
    {
      const short* g0 = gates + gr * 384 + c;
      gA[0] = (unsigned short)g0[0];
      gA[1] = (unsigned short)g0[128];
      gA[2] = (unsigned short)g0[256];
      const short* g1 = gates + GSTEP + gr * 384 + c;
      gB[0] = (unsigned short)g1[0];
      gB[1] = (unsigned short)g1[128];
      gB[2] = (unsigned short)g1[256];
    }

    __syncthreads();
    __builtin_amdgcn_s_setprio(1);

    // per-gate: sequential 4-deep MFMA chain (proven numerics), then permlane
    // redistribution so every lane holds one scalar for (row, c).
#define GATE_E(G, OUT)                                                         \
  {                                                                            \
    f32x4 cc = {0.f, 0.f, 0.f, 0.f};                                           \
    _Pragma("unroll")                                                          \
    for (int kt = 0; kt < 4; ++kt)                                             \
      cc = __builtin_amdgcn_mfma_f32_16x16x32_bf16(a_[kt], bfr[G][kt], cc, 0, 0, 0); \
    unsigned u0 = __float_as_uint(cc[0]), u2 = __float_as_uint(cc[2]);         \
    unsigned u1 = __float_as_uint(cc[1]), u3 = __float_as_uint(cc[3]);         \
    asm volatile("v_permlane32_swap_b32 %0, %1" : "+v"(u0), "+v"(u2));         \
    asm volatile("v_permlane32_swap_b32 %0, %1" : "+v"(u1), "+v"(u3));         \
    asm volatile("v_permlane16_swap_b32 %0, %1" : "+v"(u0), "+v"(u1));         \
    OUT = __uint_as_float(u0);                                                 \
  }

#define GRU_STEP(GC, BR, BW)                                                   \
  {                                                                            \
    bf16x8 a_[4];                                                              \
    _Pragma("unroll")                                                          \
    for (int kt = 0; kt < 4; ++kt)                                             \
      a_[kt] = *reinterpret_cast<const bf16x8*>(&hb[BR][lr][kt * 32 + lg * 8]);\
    float e0, e1, e2;                                                          \
    GATE_E(0, e0)                       /* r-gate first: heads the tail */     \
    float rr = sigm(u2f(GC[0]) + e0);                                          \
    GATE_E(2, e2)                       /* n-gate second */                    \
    float tt = u2f(GC[2]) + (e2 + bbn) * rr;                                   \
    float nn = 1.f - 2.f * rcpf(1.f + exp2f_(2.88539008f * tt));               \
    GATE_E(1, e1)                       /* z-gate last (needed at the end) */  \
    float zz = sigm(u2f(GC[1]) + e1);                                          \
    float hnew = nn + zz * (hold - nn);                                        \
    hb[BW][row][c] = f2b(hnew);         /* ds_write ASAP (drained by lgkm) */  \
    *hp = hold;                                                                \
    hp += HSTEP;                                                               \
    hold = hnew;                                                               \
    GC[0] = (unsigned short)*gp0;  gp0 += GSTEP;                               \
    GC[1] = (unsigned short)*gp1;  gp1 += GSTEP;                               \
    GC[2] = (unsigned short)*gp2;  gp2 += GSTEP;                               \
    asm volatile("s_waitcnt lgkmcnt(0)" ::: "memory");                         \
    __builtin_amdgcn_s_barrier();                                              \
    __builtin_amdgcn_sched_barrier(0);                                         \
  }

    for (int tt = 0; tt < 128; ++tt) {
      GRU_STEP(gA, 0, 1)
      GRU_STEP(gB, 1, 0)
    }
    __builtin_amdgcn_s_setprio(0);
#undef GRU_STEP
#undef GATE_E
  } else {
    // ---------------- x-path (obs -> relu fc -> relu fc = x_embed) ----------
    const int m0 = (blockIdx.x - 128) * 256 + w * 32;
    short (* __restrict__ B)[136] = reinterpret_cast<short (*)[136]>(&smem_[w * 32 * 136]);

    #pragma unroll
    for (int it = 0; it < 16; ++it) {
      int idx = (it * 64 + l) * 4;
      int row = idx >> 7, col = idx & 127;
      float4 v = *reinterpret_cast<const float4*>(obs + (size_t)(m0 + row) * 128 + col);
      bf16x4 p; p[0] = f2b(v.x); p[1] = f2b(v.y); p[2] = f2b(v.z); p[3] = f2b(v.w);
      *reinterpret_cast<bf16x4*>(&B[row][col]) = p;
    }

    f32x4 acc[2][8];
    bf16x8 a1f[2][4];
    #pragma unroll
    for (int mt = 0; mt < 2; ++mt)
      #pragma unroll
      for (int kt = 0; kt < 4; ++kt)
        a1f[mt][kt] = *reinterpret_cast<const bf16x8*>(&B[mt * 16 + lr][kt * 32 + lg * 8]);
    #pragma unroll
    for (int nt = 0; nt < 8; ++nt)
      #pragma unroll
      for (int mt = 0; mt < 2; ++mt) {
        f32x4 c = {0.f, 0.f, 0.f, 0.f};
        #pragma unroll
        for (int kt = 0; kt < 4; ++kt) {
          bf16x8 bv = *reinterpret_cast<const bf16x8*>(xw1 + (size_t)(nt * 16 + lr) * 128 + kt * 32 + lg * 8);
          c = __builtin_amdgcn_mfma_f32_16x16x32_bf16(a1f[mt][kt], bv, c, 0, 0, 0);
        }
        acc[mt][nt] = c;
      }
    #pragma unroll
    for (int nt = 0; nt < 8; ++nt) {
      float bb = xb1[nt * 16 + lr];
      #pragma unroll
      for (int mt = 0; mt < 2; ++mt)
        #pragma unroll
        for (int r = 0; r < 4; ++r) {
          float v = acc[mt][nt][r] + bb;
          B[mt * 16 + lg * 4 + r][nt * 16 + lr] = f2b(v > 0.f ? v : 0.f);
        }
    }

    bf16x8 a2f[2][4];
    #pragma unroll
    for (int mt = 0; mt < 2; ++mt)
      #pragma unroll
      for (int kt = 0; kt < 4; ++kt)
        a2f[mt][kt] = *reinterpret_cast<const bf16x8*>(&B[mt * 16 + lr][kt * 32 + lg * 8]);
    #pragma unroll
    for (int nt = 0; nt < 8; ++nt) {
      float bb = xb2[nt * 16 + lr];
      #pragma unroll
      for (int mt = 0; mt < 2; ++mt) {
        f32x4 c = {0.f, 0.f, 0.f, 0.f};
        #pragma unroll
        for (int kt = 0; kt < 4; ++kt) {
          bf16x8 bv = *reinterpret_cast<const bf16x8*>(xw2 + (size_t)(nt * 16 + lr) * 128 + kt * 32 + lg * 8);
          c = __builtin_amdgcn_mfma_f32_16x16x32_bf16(a2f[mt][kt], bv, c, 0, 0, 0);
        }
        #pragma unroll
        for (int r = 0; r < 4; ++r) {
          float v = c[r] + bb;
          xe[(size_t)(m0 + mt * 16 + lg * 4 + r) * 128 + nt * 16 + lr] = (v > 0.f ? v : 0.f);
        }
      }
    }
  }
}

// ---------------------------------------------------------------------------
// K4: posterior DBlock + reparam (R12 64-row version). NEW (R13): the wf2 and
// wm/wl weight streams ISSUE BEFORE b1 — the lgkm-only barrier leaves them in
// flight, gaining the barrier+stage window of L2 latency cover before ph1.
// eps loads likewise issue with the stage. No arithmetic-order changes.
// ---------------------------------------------------------------------------
#define PT 4
__global__ __launch_bounds__(512) void k_post(
    const float* __restrict__ xe, const float* __restrict__ hs, const float* __restrict__ eps,
    const short* __restrict__ pw1, const float* __restrict__ pb1,
    const short* __restrict__ pw2, const float* __restrict__ pb2,
    const short* __restrict__ pwmu, const float* __restrict__ pbmu,
    const short* __restrict__ pwls, const float* __restrict__ pbls,
    float* __restrict__ mu, float* __restrict__ ls, float* __restrict__ samp)
{
  __shared__ short Ab[64][264];
  const int tid = threadIdx.x, w = tid >> 6, l = tid & 63;
  const int lr = l & 15, lg = l >> 4;
  const int srow = tid >> 4, scol = (tid & 15) * 8;
  const int n2 = w * 16 + lr;           // ph2 output column (mu & ls)

  bf16x8 wf1[2][8];
  float bb1[2], bb2[2];
  #pragma unroll
  for (int j = 0; j < 2; ++j) {
    const int n = w * 32 + j * 16 + lr;
    bb1[j] = pb1[n]; bb2[j] = pb2[n];
    #pragma unroll
    for (int kt = 0; kt < 8; ++kt)
      wf1[j][kt] = *reinterpret_cast<const bf16x8*>(pw1 + (size_t)n * 256 + kt * 32 + lg * 8);
  }
  const float bbm = pbmu[n2], bbl = pbls[n2];

  // T14 preload: tile-0 stage regs (two 32-row halves)
  float4 sx0[2], sx1[2], sh0[2], sh1[2];
  {
    const size_t m0 = (size_t)blockIdx.x * PT * 64;
    #pragma unroll
    for (int h = 0; h < 2; ++h) {
      const float* px = xe + (m0 + srow + 32 * h) * 128 + scol;
      sx0[h] = *reinterpret_cast<const float4*>(px);
      sx1[h] = *reinterpret_cast<const float4*>(px + 4);
      const float* ph = hs + (m0 + srow + 32 * h) * 128 + scol;
      sh0[h] = *reinterpret_cast<const float4*>(ph);
      sh1[h] = *reinterpret_cast<const float4*>(ph + 4);
    }
  }

  for (int it = 0; it < PT; ++it) {
    const size_t m0 = ((size_t)blockIdx.x * PT + it) * 64;

    unsigned long long a2 = (unsigned long long)pw2;
    unsigned long long am_ = (unsigned long long)pwmu;
    unsigned long long al_ = (unsigned long long)pwls;
    asm volatile("" : "+s"(a2), "+s"(am_), "+s"(al_));
    const short* pw2v = (const short*)a2;
    const short* pwmv = (const short*)am_;
    const short* pwlv = (const short*)al_;

    // --- issue ALL this tile's weight streams + eps BEFORE the barrier ---
    bf16x8 wf2[2][8];
    #pragma unroll
    for (int j = 0; j < 2; ++j) {
      const int n = w * 32 + j * 16 + lr;
      #pragma unroll
      for (int kt = 0; kt < 8; ++kt)
        wf2[j][kt] = *reinterpret_cast<const bf16x8*>(pw2v + (size_t)n * 256 + kt * 32 + lg * 8);
    }
    bf16x8 wm[8], wl[8];
    #pragma unroll
    for (int kt = 0; kt < 8; ++kt) {
      wm[kt] = *reinterpret_cast<const bf16x8*>(pwmv + (size_t)n2 * 256 + kt * 32 + lg * 8);
      wl[kt] = *reinterpret_cast<const bf16x8*>(pwlv + (size_t)n2 * 256 + kt * 32 + lg * 8);
    }
    float ev[4][4];
    #pragma unroll
    for (int mt = 0; mt < 4; ++mt)
      #pragma unroll
      for (int r = 0; r < 4; ++r)
        ev[mt][r] = eps[(m0 + mt * 16 + lg * 4 + r) * 128 + n2];

    // write the PRE-LOADED stage regs to LDS (rows m0..m0+63)
    #pragma unroll
    for (int h = 0; h < 2; ++h) {
      const int row = srow + 32 * h;
      bf16x8 pk;
      pk[0] = f2b(sx0[h].x); pk[1] = f2b(sx0[h].y); pk[2] = f2b(sx0[h].z); pk[3] = f2b(sx0[h].w);
      pk[4] = f2b(sx1[h].x); pk[5] = f2b(sx1[h].y); pk[6] = f2b(sx1[h].z); pk[7] = f2b(sx1[h].w);
      *reinterpret_cast<bf16x8*>(&Ab[row][scol]) = pk;
      bf16x8 qk;
      qk[0] = f2b(sh0[h].x); qk[1] = f2b(sh0[h].y); qk[2] = f2b(sh0[h].z); qk[3] = f2b(sh0[h].w);
      qk[4] = f2b(sh1[h].x); qk[5] = f2b(sh1[h].y); qk[6] = f2b(sh1[h].z); qk[7] = f2b(sh1[h].w);
      *reinterpret_cast<bf16x8*>(&Ab[row][128 + scol]) = qk;
    }
    LGKM_BAR();  // b1: A staged (weight streams remain in flight)

    // T14: issue NEXT tile's xe/hs loads now — they return during ph1/ph2
    {
      const size_t mn = ((size_t)blockIdx.x * PT + (it + 1 < PT ? it + 1 : it)) * 64;
      #pragma unroll
      for (int h = 0; h < 2; ++h) {
        const float* px = xe + (mn + srow + 32 * h) * 128 + scol;
        sx0[h] = *reinterpret_cast<const float4*>(px);
        sx1[h] = *reinterpret_cast<const float4*>(px + 4);
        const float* ph = hs + (mn + srow + 32 * h) * 128 + scol;
        sh0[h] = *reinterpret_cast<const float4*>(ph);
        sh1[h] = *reinterpret_cast<const float4*>(ph + 4);
      }
    }

    // ph1: t = relu(A@w1^T+b1)*sigm(A@w2^T+b2), wave w -> cols w*32+j*16+lr
    f32x4 ac1[2][4], ac2[2][4];   // [j][mt], mt = 4 row-tiles (64 rows)
    #pragma unroll
    for (int j = 0; j < 2; ++j)
      #pragma unroll
      for (int mt = 0; mt < 4; ++mt) { ac1[j][mt] = (f32x4){0.f,0.f,0.f,0.f}; ac2[j][mt] = (f32x4){0.f,0.f,0.f,0.f}; }
    #pragma unroll
    for (int kt = 0; kt < 8; ++kt) {
      bf16x8 af[4];
      #pragma unroll
      for (int mt = 0; mt < 4; ++mt)
        af[mt] = *reinterpret_cast<const bf16x8*>(&Ab[mt * 16 + lr][kt * 32 + lg * 8]);
      #pragma unroll
      for (int j = 0; j < 2; ++j)
        #pragma unroll
        for (int mt = 0; mt < 4; ++mt) {
          ac1[j][mt] = __builtin_amdgcn_mfma_f32_16x16x32_bf16(af[mt], wf1[j][kt], ac1[j][mt], 0, 0, 0);
          ac2[j][mt] = __builtin_amdgcn_mfma_f32_16x16x32_bf16(af[mt], wf2[j][kt], ac2[j][mt], 0, 0, 0);
        }
    }
    LGKM_BAR();  // b2: all A reads done; t may overlay Ab

    #pragma unroll
    for (int j = 0; j < 2; ++j)
      #pragma unroll
      for (int mt = 0; mt < 4; ++mt)
        #pragma unroll
        for (int r = 0; r < 4; ++r) {
          float t1 = ac1[j][mt][r] + bb1[j]; t1 = t1 > 0.f ? t1 : 0.f;
          float t2 = sigm(ac2[j][mt][r] + bb2[j]);
          Ab[mt * 16 + lg * 4 + r][w * 32 + j * 16 + lr] = f2b(t1 * t2);  // rows<64, cols<256: in-bounds
        }
    LGKM_BAR();  // b3: t ready

    // ph2: mu/ls = t @ {wmu,wls}^T + reparam sample
    f32x4 amc[4], alc[4];
    #pragma unroll
    for (int mt = 0; mt < 4; ++mt) { amc[mt] = (f32x4){0.f,0.f,0.f,0.f}; alc[mt] = (f32x4){0.f,0.f,0.f,0.f}; }
    #pragma unroll
    for (int kt = 0; kt < 8; ++kt) {
      #pragma unroll
      for (int mt = 0; mt < 4; ++mt) {
        bf16x8 at = *reinterpret_cast<const bf16x8*>(&Ab[mt * 16 + lr][kt * 32 + lg * 8]);
        amc[mt] = __builtin_amdgcn_mfma_f32_16x16x32_bf16(at, wm[kt], amc[mt], 0, 0, 0);
        alc[mt] = __builtin_amdgcn_mfma_f32_16x16x32_bf16(at, wl[kt], alc[mt], 0, 0, 0);
      }
    }
    #pragma unroll
    for (int mt = 0; mt < 4; ++mt)
      #pragma unroll
      for (int r = 0; r < 4; ++r) {
        size_t off = (m0 + mt * 16 + lg * 4 + r) * 128 + n2;
        float m_ = amc[mt][r] + bbm;
        float l_ = alc[mt][r] + bbl;
        mu[off] = m_;
        ls[off] = l_;
        samp[off] = m_ + exp2f_(1.44269504f * l_) * ev[mt][r];
      }
    LGKM_BAR();  // b4: t consumed before next tile's stage overwrites
  }
}

// ---------------------------------------------------------------------------
extern "C" void kernel_launch(void* const* d_in, const int* in_sizes, int n_in,
                              void* d_out, int out_size, void* d_ws, size_t ws_size,
                              hipStream_t stream) {
  const float* ext   = (const float*)d_in[0];
  const float* obs   = (const float*)d_in[1];
  const float* eps   = (const float*)d_in[2];
  const float* u_w1  = (const float*)d_in[3];
  const float* u_b1  = (const float*)d_in[4];
  const float* u_w2  = (const float*)d_in[5];
  const float* u_b2  = (const float*)d_in[6];
  const float* x_w1  = (const float*)d_in[7];
  const float* x_b1  = (const float*)d_in[8];
  const float* x_w2  = (const float*)d_in[9];
  const float* x_b2  = (const float*)d_in[10];
  const float* pw1   = (const float*)d_in[11];
  const float* pb1   = (const float*)d_in[12];
  const float* pw2   = (const float*)d_in[13];
  const float* pb2   = (const float*)d_in[14];
  const float* pwmu  = (const float*)d_in[15];
  const float* pbmu  = (const float*)d_in[16];
  const float* pwls  = (const float*)d_in[17];
  const float* pbls  = (const float*)d_in[18];
  const float* g_wih = (const float*)d_in[19];
  const float* g_whh = (const float*)d_in[20];
  const float* g_bih = (const float*)d_in[21];
  const float* g_bhh = (const float*)d_in[22];

  float* out = (float*)d_out;
  float* o_mu = out;
  float* o_ls = out + 16777216;
  float* o_sp = out + 33554432;
  float* o_hs = out + 50331648;
  float* o_xe = out + 67108864;
  // bf16 x_gates scratch (L*B*384 shorts = 100 MB) lives at the start of the
  // output region; fully consumed by k_grux before k_post overwrites it.
  short* gates = (short*)out;

  short* wb = (short*)d_ws;
  short* c_uw1  = wb + 0;
  short* c_uw2  = wb + 8192;
  short* c_xw1  = wb + 24576;
  short* c_xw2  = wb + 40960;
  short* c_wih  = wb + 57344;
  short* c_whh  = wb + 106496;
  short* c_pw1  = wb + 155648;
  short* c_pw2  = wb + 221184;
  short* c_pwmu = wb + 286720;
  short* c_pwls = wb + 319488;

  k_cvt<<<1376, 256, 0, stream>>>(u_w1, u_w2, x_w1, x_w2, g_wih, g_whh,
                                  pw1, pw2, pwmu, pwls, wb);
  k_upath<<<512, 512, 0, stream>>>(ext, c_uw1, u_b1, c_uw2, u_b2, c_wih, g_bih, g_bhh, gates);
  k_grux<<<640, 512, 0, stream>>>(gates, c_whh, g_bhh, o_hs,
                                  obs, c_xw1, x_b1, c_xw2, x_b2, o_xe);
  k_post<<<512, 512, 0, stream>>>(o_xe, o_hs, eps, c_pw1, pb1, c_pw2, pb2,
                                  c_pwmu, pbmu, c_pwls, pbls, o_mu, o_ls, o_sp);
}

// Round 14
// 350.146 us; speedup vs baseline: 1.2291x; 1.2291x over previous
//
#include <hip/hip_runtime.h>

// ---------------------------------------------------------------------------
// VAERNN forward posterior, MI355X bf16-MFMA implementation.
// L=256 B=512 K=128 IN=64 STATE=128 OBS=128, LB = L*B = 131072 rows.
// ---------------------------------------------------------------------------

typedef __attribute__((ext_vector_type(8))) short bf16x8;
typedef __attribute__((ext_vector_type(4))) short bf16x4;
typedef __attribute__((ext_vector_type(4))) float f32x4;

#define LB 131072

__device__ __forceinline__ short f2b(float f) {
  union { float f; unsigned u; } v; v.f = f;
  unsigned r = (v.u + 0x7FFFu + ((v.u >> 16) & 1u)) >> 16;  // RNE
  return (short)r;
}
__device__ __forceinline__ float u2f(unsigned u) {
  union { unsigned u; float f; } v; v.u = u << 16; return v.f;
}
__device__ __forceinline__ float rcpf(float x) { return __builtin_amdgcn_rcpf(x); }
__device__ __forceinline__ float exp2f_(float x) { return __builtin_amdgcn_exp2f(x); }
__device__ __forceinline__ float sigm(float x) { return rcpf(1.f + exp2f_(-1.44269504f * x)); }

// lgkm-only barrier: LDS ordering without draining global loads/stores (T4).
#define LGKM_BAR()                                          \
  asm volatile("s_waitcnt lgkmcnt(0)" ::: "memory");        \
  __builtin_amdgcn_s_barrier();                             \
  __builtin_amdgcn_sched_barrier(0);

// ---------------------------------------------------------------------------
// K0: convert all weight matrices fp32 -> bf16 into workspace (contiguous).
// ---------------------------------------------------------------------------
__global__ __launch_bounds__(256) void k_cvt(
    const float* __restrict__ s0, const float* __restrict__ s1,
    const float* __restrict__ s2, const float* __restrict__ s3,
    const float* __restrict__ s4, const float* __restrict__ s5,
    const float* __restrict__ s6, const float* __restrict__ s7,
    const float* __restrict__ s8, const float* __restrict__ s9,
    short* __restrict__ dst)
{
  int i = blockIdx.x * 256 + threadIdx.x;
  if (i >= 352256) return;
  const float* src; int off;
  if      (i <   8192) { src = s0; off = i; }
  else if (i <  24576) { src = s1; off = i - 8192; }
  else if (i <  40960) { src = s2; off = i - 24576; }
  else if (i <  57344) { src = s3; off = i - 40960; }
  else if (i < 106496) { src = s4; off = i - 57344; }
  else if (i < 155648) { src = s5; off = i - 106496; }
  else if (i < 221184) { src = s6; off = i - 155648; }
  else if (i < 286720) { src = s7; off = i - 221184; }
  else if (i < 319488) { src = s8; off = i - 286720; }
  else                 { src = s9; off = i - 319488; }
  dst[i] = f2b(src[off]);
}

// ---------------------------------------------------------------------------
// K1: u-path: x(64) -> relu fc(128) -> relu fc(128) -> gates(384).
// 512 blocks x 512 thr, grid-stride 8 tiles of 32 rows. ALL weights
// register-resident. T14: next tile's x-loads issued right after b1.
// (R11 version — proven.)
// ---------------------------------------------------------------------------
#define UT 8
__global__ __launch_bounds__(512) void k_upath(
    const float* __restrict__ x, const short* __restrict__ w1, const float* __restrict__ b1,
    const short* __restrict__ w2, const float* __restrict__ b2,
    const short* __restrict__ wih, const float* __restrict__ bih,
    const float* __restrict__ bhh,
    short* __restrict__ gates)
{
  __shared__ short Xb[32][72];
  __shared__ short Tb[32][136];
  __shared__ short Gb[32][392];
  const int tid = threadIdx.x, w = tid >> 6, l = tid & 63;
  const int lr = l & 15, lg = l >> 4;
  const int n1 = w * 16 + lr;   // this lane's layer1/layer2 output column

  bf16x8 wf1[2], wf2[4], wfg[3][4];
  #pragma unroll
  for (int kt = 0; kt < 2; ++kt)
    wf1[kt] = *reinterpret_cast<const bf16x8*>(w1 + (size_t)n1 * 64 + kt * 32 + lg * 8);
  #pragma unroll
  for (int kt = 0; kt < 4; ++kt)
    wf2[kt] = *reinterpret_cast<const bf16x8*>(w2 + (size_t)n1 * 128 + kt * 32 + lg * 8);
  float bgv[3];
  #pragma unroll
  for (int j = 0; j < 3; ++j) {
    const int cg = w * 48 + j * 16 + lr;
    bgv[j] = bih[cg] + (cg < 256 ? bhh[cg] : 0.f);  // fold bhh into r/z gates
    #pragma unroll
    for (int kt = 0; kt < 4; ++kt)
      wfg[j][kt] = *reinterpret_cast<const bf16x8*>(wih + (size_t)cg * 128 + kt * 32 + lg * 8);
  }
  const float b1v = b1[n1], b2v = b2[n1];
  const int srow = tid >> 4, scol4 = (tid & 15) * 4, gcol = (tid & 15) * 24;

  // preload tile-0 stage regs (T14)
  float4 sx = *reinterpret_cast<const float4*>(
      x + ((size_t)blockIdx.x * UT * 32 + srow) * 64 + scol4);

  for (int it = 0; it < UT; ++it) {
    const size_t m0 = ((size_t)blockIdx.x * UT + it) * 32;

    // write staged x tile (32 x 64) as bf16
    {
      bf16x4 p; p[0] = f2b(sx.x); p[1] = f2b(sx.y); p[2] = f2b(sx.z); p[3] = f2b(sx.w);
      *reinterpret_cast<bf16x4*>(&Xb[srow][scol4]) = p;
    }
    LGKM_BAR();  // b1: x staged (also drains prev tile's Gb readback reads)

    // T14: issue next tile's x-load now (clamped; hidden under MFMAs below)
    {
      const size_t mn = ((size_t)blockIdx.x * UT + (it + 1 < UT ? it + 1 : it)) * 32;
      sx = *reinterpret_cast<const float4*>(x + (mn + srow) * 64 + scol4);
    }

    // layer1: K=64 -> 16 cols/wave
    f32x4 a1c[2] = {(f32x4){0.f,0.f,0.f,0.f}, (f32x4){0.f,0.f,0.f,0.f}};
    #pragma unroll
    for (int kt = 0; kt < 2; ++kt) {
      #pragma unroll
      for (int mt = 0; mt < 2; ++mt) {
        bf16x8 af = *reinterpret_cast<const bf16x8*>(&Xb[mt * 16 + lr][kt * 32 + lg * 8]);
        a1c[mt] = __builtin_amdgcn_mfma_f32_16x16x32_bf16(af, wf1[kt], a1c[mt], 0, 0, 0);
      }
    }
    #pragma unroll
    for (int mt = 0; mt < 2; ++mt)
      #pragma unroll
      for (int r = 0; r < 4; ++r) {
        float v = a1c[mt][r] + b1v;
        Tb[mt * 16 + lg * 4 + r][n1] = f2b(v > 0.f ? v : 0.f);
      }
    LGKM_BAR();  // b2: layer1 exchanged

    // layer2: K=128 -> 16 cols/wave; output exchanged via Gb[.][0..127]
    f32x4 a2c[2] = {(f32x4){0.f,0.f,0.f,0.f}, (f32x4){0.f,0.f,0.f,0.f}};
    #pragma unroll
    for (int kt = 0; kt < 4; ++kt) {
      #pragma unroll
      for (int mt = 0; mt < 2; ++mt) {
        bf16x8 af = *reinterpret_cast<const bf16x8*>(&Tb[mt * 16 + lr][kt * 32 + lg * 8]);
        a2c[mt] = __builtin_amdgcn_mfma_f32_16x16x32_bf16(af, wf2[kt], a2c[mt], 0, 0, 0);
      }
    }
    #pragma unroll
    for (int mt = 0; mt < 2; ++mt)
      #pragma unroll
      for (int r = 0; r < 4; ++r) {
        float v = a2c[mt][r] + b2v;
        Gb[mt * 16 + lg * 4 + r][n1] = f2b(v > 0.f ? v : 0.f);
      }
    LGKM_BAR();  // b3: u_embed exchanged

    // gates: read A-frags first (regs), then barrier, then overwrite Gb
    bf16x8 ag[2][4];
    #pragma unroll
    for (int mt = 0; mt < 2; ++mt)
      #pragma unroll
      for (int kt = 0; kt < 4; ++kt)
        ag[mt][kt] = *reinterpret_cast<const bf16x8*>(&Gb[mt * 16 + lr][kt * 32 + lg * 8]);
    LGKM_BAR();  // b4: all u_embed reads done; Gb free for gate outputs

    #pragma unroll
    for (int j = 0; j < 3; ++j) {
      #pragma unroll
      for (int mt = 0; mt < 2; ++mt) {
        f32x4 c = {0.f, 0.f, 0.f, 0.f};
        #pragma unroll
        for (int kt = 0; kt < 4; ++kt)
          c = __builtin_amdgcn_mfma_f32_16x16x32_bf16(ag[mt][kt], wfg[j][kt], c, 0, 0, 0);
        #pragma unroll
        for (int r = 0; r < 4; ++r)
          Gb[mt * 16 + lg * 4 + r][w * 48 + j * 16 + lr] = f2b(c[r] + bgv[j]);
      }
    }
    LGKM_BAR();  // b5: gate tile assembled

    // vectorized readback + coalesced global store (row: 16 lanes x 48B)
    #pragma unroll
    for (int k = 0; k < 3; ++k) {
      bf16x8 vv = *reinterpret_cast<const bf16x8*>(&Gb[srow][gcol + k * 8]);
      *reinterpret_cast<bf16x8*>(gates + (m0 + srow) * 384 + gcol + k * 8) = vv;
    }
    // next tile's b1 drains these LDS reads before Gb is rewritten
  }
}

// ---------------------------------------------------------------------------
// K2: fused GRU scan + x-path (heterogeneous blocks). (R13 grux — kept:
// strength-reduced gate/hseq pointers, register-neutral.)
// LDS padded past 80 KB -> 1 block/CU. Blocks 0..127: GRU, sequential 4-deep
// MFMA chains, permlane full redistribution, setprio(1).
// Blocks 128..639: x-path embedding.
// ---------------------------------------------------------------------------
__global__ __launch_bounds__(512) void k_grux(
    const short* __restrict__ gates, const short* __restrict__ whh,
    const float* __restrict__ bhh, float* __restrict__ hseq,
    const float* __restrict__ obs, const short* __restrict__ xw1,
    const float* __restrict__ xb1, const short* __restrict__ xw2,
    const float* __restrict__ xb2, float* __restrict__ xe)
{
  __shared__ short smem_[41088];   // 82176 B > 80 KB -> 1 block/CU (exclusivity)
  const int tid = threadIdx.x, w = tid >> 6, l = tid & 63;
  const int lr = l & 15, lg = l >> 4;

  if (blockIdx.x < 128) {
    // ---------------- GRU path ----------------
    short (*hb)[16][136] = reinterpret_cast<short (*)[16][136]>(smem_);
    const int m0 = blockIdx.x * 4;
    const int c = w * 16 + lr;   // this lane's h/gate column (0..127)
    const int row = lg;          // this lane's batch row within tile (0..3)
    const size_t gr = m0 + row;  // global batch row

    bf16x8 bfr[3][4];
    #pragma unroll
    for (int g = 0; g < 3; ++g)
      #pragma unroll
      for (int kt = 0; kt < 4; ++kt)
        bfr[g][kt] = *reinterpret_cast<const bf16x8*>(whh + (size_t)(g * 128 + c) * 128 + kt * 32 + lg * 8);
    const float bbn = bhh[256 + c];  // only the n-gate bias survives (scaled by r)

    for (int i = tid; i < 2 * 16 * 136; i += 512) smem_[i] = 0;

    float hold = 0.f;

    // strength-reduced pointers:
    //   gate prefetch: 1 pointer per gate at (t=2)-position, += GSTEP/step
    //   hseq store:    1 pointer at t=0 position, += HSTEP/step
    // The 2-step-ahead prefetch runs past the gates region by <=0.8 MB into
    // the (valid, unread) output buffer — loads only, values never consumed.
    const size_t GSTEP = (size_t)512 * 384;   // shorts per timestep in gates
    const size_t HSTEP = (size_t)512 * 128;   // floats per timestep in hseq
    const short* gp0 = gates + (size_t)2 * GSTEP + gr * 384 + 0 * 128 + c;
    const short* gp1 = gates + (size_t)2 * GSTEP + gr * 384 + 1 * 128 + c;
    const short* gp2 = gates + (size_t)2 * GSTEP + gr * 384 + 2 * 128 + c;
    float* hp = hseq + gr * 128 + c;

    unsigned gA[3], gB[3];
    {
      const short* g0 = gates + gr * 384 + c;
      gA[0] = (unsigned short)g0[0];
      gA[1] = (unsigned short)g0[128];
      gA[2] = (unsigned short)g0[256];
      const short* g1 = gates + GSTEP + gr * 384 + c;
      gB[0] = (unsigned short)g1[0];
      gB[1] = (unsigned short)g1[128];
      gB[2] = (unsigned short)g1[256];
    }

    __syncthreads();
    __builtin_amdgcn_s_setprio(1);

    // per-gate: sequential 4-deep MFMA chain (proven numerics), then permlane
    // redistribution so every lane holds one scalar for (row, c).
#define GATE_E(G, OUT)                                                         \
  {                                                                            \
    f32x4 cc = {0.f, 0.f, 0.f, 0.f};                                           \
    _Pragma("unroll")                                                          \
    for (int kt = 0; kt < 4; ++kt)                                             \
      cc = __builtin_amdgcn_mfma_f32_16x16x32_bf16(a_[kt], bfr[G][kt], cc, 0, 0, 0); \
    unsigned u0 = __float_as_uint(cc[0]), u2 = __float_as_uint(cc[2]);         \
    unsigned u1 = __float_as_uint(cc[1]), u3 = __float_as_uint(cc[3]);         \
    asm volatile("v_permlane32_swap_b32 %0, %1" : "+v"(u0), "+v"(u2));         \
    asm volatile("v_permlane32_swap_b32 %0, %1" : "+v"(u1), "+v"(u3));         \
    asm volatile("v_permlane16_swap_b32 %0, %1" : "+v"(u0), "+v"(u1));         \
    OUT = __uint_as_float(u0);                                                 \
  }

#define GRU_STEP(GC, BR, BW)                                                   \
  {                                                                            \
    bf16x8 a_[4];                                                              \
    _Pragma("unroll")                                                          \
    for (int kt = 0; kt < 4; ++kt)                                             \
      a_[kt] = *reinterpret_cast<const bf16x8*>(&hb[BR][lr][kt * 32 + lg * 8]);\
    float e0, e1, e2;                                                          \
    GATE_E(0, e0)                       /* r-gate first: heads the tail */     \
    float rr = sigm(u2f(GC[0]) + e0);                                          \
    GATE_E(2, e2)                       /* n-gate second */                    \
    float tt = u2f(GC[2]) + (e2 + bbn) * rr;                                   \
    float nn = 1.f - 2.f * rcpf(1.f + exp2f_(2.88539008f * tt));               \
    GATE_E(1, e1)                       /* z-gate last (needed at the end) */  \
    float zz = sigm(u2f(GC[1]) + e1);                                          \
    float hnew = nn + zz * (hold - nn);                                        \
    hb[BW][row][c] = f2b(hnew);         /* ds_write ASAP (drained by lgkm) */  \
    *hp = hold;                                                                \
    hp += HSTEP;                                                               \
    hold = hnew;                                                               \
    GC[0] = (unsigned short)*gp0;  gp0 += GSTEP;                               \
    GC[1] = (unsigned short)*gp1;  gp1 += GSTEP;                               \
    GC[2] = (unsigned short)*gp2;  gp2 += GSTEP;                               \
    asm volatile("s_waitcnt lgkmcnt(0)" ::: "memory");                         \
    __builtin_amdgcn_s_barrier();                                              \
    __builtin_amdgcn_sched_barrier(0);                                         \
  }

    for (int tt = 0; tt < 128; ++tt) {
      GRU_STEP(gA, 0, 1)
      GRU_STEP(gB, 1, 0)
    }
    __builtin_amdgcn_s_setprio(0);
#undef GRU_STEP
#undef GATE_E
  } else {
    // ---------------- x-path (obs -> relu fc -> relu fc = x_embed) ----------
    const int m0 = (blockIdx.x - 128) * 256 + w * 32;
    short (* __restrict__ B)[136] = reinterpret_cast<short (*)[136]>(&smem_[w * 32 * 136]);

    #pragma unroll
    for (int it = 0; it < 16; ++it) {
      int idx = (it * 64 + l) * 4;
      int row = idx >> 7, col = idx & 127;
      float4 v = *reinterpret_cast<const float4*>(obs + (size_t)(m0 + row) * 128 + col);
      bf16x4 p; p[0] = f2b(v.x); p[1] = f2b(v.y); p[2] = f2b(v.z); p[3] = f2b(v.w);
      *reinterpret_cast<bf16x4*>(&B[row][col]) = p;
    }

    f32x4 acc[2][8];
    bf16x8 a1f[2][4];
    #pragma unroll
    for (int mt = 0; mt < 2; ++mt)
      #pragma unroll
      for (int kt = 0; kt < 4; ++kt)
        a1f[mt][kt] = *reinterpret_cast<const bf16x8*>(&B[mt * 16 + lr][kt * 32 + lg * 8]);
    #pragma unroll
    for (int nt = 0; nt < 8; ++nt)
      #pragma unroll
      for (int mt = 0; mt < 2; ++mt) {
        f32x4 c = {0.f, 0.f, 0.f, 0.f};
        #pragma unroll
        for (int kt = 0; kt < 4; ++kt) {
          bf16x8 bv = *reinterpret_cast<const bf16x8*>(xw1 + (size_t)(nt * 16 + lr) * 128 + kt * 32 + lg * 8);
          c = __builtin_amdgcn_mfma_f32_16x16x32_bf16(a1f[mt][kt], bv, c, 0, 0, 0);
        }
        acc[mt][nt] = c;
      }
    #pragma unroll
    for (int nt = 0; nt < 8; ++nt) {
      float bb = xb1[nt * 16 + lr];
      #pragma unroll
      for (int mt = 0; mt < 2; ++mt)
        #pragma unroll
        for (int r = 0; r < 4; ++r) {
          float v = acc[mt][nt][r] + bb;
          B[mt * 16 + lg * 4 + r][nt * 16 + lr] = f2b(v > 0.f ? v : 0.f);
        }
    }

    bf16x8 a2f[2][4];
    #pragma unroll
    for (int mt = 0; mt < 2; ++mt)
      #pragma unroll
      for (int kt = 0; kt < 4; ++kt)
        a2f[mt][kt] = *reinterpret_cast<const bf16x8*>(&B[mt * 16 + lr][kt * 32 + lg * 8]);
    #pragma unroll
    for (int nt = 0; nt < 8; ++nt) {
      float bb = xb2[nt * 16 + lr];
      #pragma unroll
      for (int mt = 0; mt < 2; ++mt) {
        f32x4 c = {0.f, 0.f, 0.f, 0.f};
        #pragma unroll
        for (int kt = 0; kt < 4; ++kt) {
          bf16x8 bv = *reinterpret_cast<const bf16x8*>(xw2 + (size_t)(nt * 16 + lr) * 128 + kt * 32 + lg * 8);
          c = __builtin_amdgcn_mfma_f32_16x16x32_bf16(a2f[mt][kt], bv, c, 0, 0, 0);
        }
        #pragma unroll
        for (int r = 0; r < 4; ++r) {
          float v = c[r] + bb;
          xe[(size_t)(m0 + mt * 16 + lg * 4 + r) * 128 + nt * 16 + lr] = (v > 0.f ? v : 0.f);
        }
      }
    }
  }
}

// ---------------------------------------------------------------------------
// K4: posterior DBlock + reparam — EXACT R12 version (R13's pre-issued weight
// streams blew the VGPR budget: 128 VGPR + ~220 MB scratch spill traffic,
// k_post 105 -> 240 µs; reverted). 512 blocks x 512 thr, 4 tiles of 64 rows.
// fc1 register-resident; fc2/mu/ls streamed per tile (anti-LICM). T14
// async-stage of next tile's xe/hs. lgkm-only barriers.
// ---------------------------------------------------------------------------
#define PT 4
__global__ __launch_bounds__(512) void k_post(
    const float* __restrict__ xe, const float* __restrict__ hs, const float* __restrict__ eps,
    const short* __restrict__ pw1, const float* __restrict__ pb1,
    const short* __restrict__ pw2, const float* __restrict__ pb2,
    const short* __restrict__ pwmu, const float* __restrict__ pbmu,
    const short* __restrict__ pwls, const float* __restrict__ pbls,
    float* __restrict__ mu, float* __restrict__ ls, float* __restrict__ samp)
{
  __shared__ short Ab[64][264];
  const int tid = threadIdx.x, w = tid >> 6, l = tid & 63;
  const int lr = l & 15, lg = l >> 4;
  const int srow = tid >> 4, scol = (tid & 15) * 8;
  const int n2 = w * 16 + lr;           // ph2 output column (mu & ls)

  bf16x8 wf1[2][8];
  float bb1[2], bb2[2];
  #pragma unroll
  for (int j = 0; j < 2; ++j) {
    const int n = w * 32 + j * 16 + lr;
    bb1[j] = pb1[n]; bb2[j] = pb2[n];
    #pragma unroll
    for (int kt = 0; kt < 8; ++kt)
      wf1[j][kt] = *reinterpret_cast<const bf16x8*>(pw1 + (size_t)n * 256 + kt * 32 + lg * 8);
  }
  const float bbm = pbmu[n2], bbl = pbls[n2];

  // T14 preload: tile-0 stage regs (two 32-row halves)
  float4 sx0[2], sx1[2], sh0[2], sh1[2];
  {
    const size_t m0 = (size_t)blockIdx.x * PT * 64;
    #pragma unroll
    for (int h = 0; h < 2; ++h) {
      const float* px = xe + (m0 + srow + 32 * h) * 128 + scol;
      sx0[h] = *reinterpret_cast<const float4*>(px);
      sx1[h] = *reinterpret_cast<const float4*>(px + 4);
      const float* ph = hs + (m0 + srow + 32 * h) * 128 + scol;
      sh0[h] = *reinterpret_cast<const float4*>(ph);
      sh1[h] = *reinterpret_cast<const float4*>(ph + 4);
    }
  }

  for (int it = 0; it < PT; ++it) {
    const size_t m0 = ((size_t)blockIdx.x * PT + it) * 64;

    unsigned long long a2 = (unsigned long long)pw2;
    unsigned long long am_ = (unsigned long long)pwmu;
    unsigned long long al_ = (unsigned long long)pwls;
    asm volatile("" : "+s"(a2), "+s"(am_), "+s"(al_));
    const short* pw2v = (const short*)a2;
    const short* pwmv = (const short*)am_;
    const short* pwlv = (const short*)al_;

    // write the PRE-LOADED stage regs to LDS (rows m0..m0+63)
    #pragma unroll
    for (int h = 0; h < 2; ++h) {
      const int row = srow + 32 * h;
      bf16x8 pk;
      pk[0] = f2b(sx0[h].x); pk[1] = f2b(sx0[h].y); pk[2] = f2b(sx0[h].z); pk[3] = f2b(sx0[h].w);
      pk[4] = f2b(sx1[h].x); pk[5] = f2b(sx1[h].y); pk[6] = f2b(sx1[h].z); pk[7] = f2b(sx1[h].w);
      *reinterpret_cast<bf16x8*>(&Ab[row][scol]) = pk;
      bf16x8 qk;
      qk[0] = f2b(sh0[h].x); qk[1] = f2b(sh0[h].y); qk[2] = f2b(sh0[h].z); qk[3] = f2b(sh0[h].w);
      qk[4] = f2b(sh1[h].x); qk[5] = f2b(sh1[h].y); qk[6] = f2b(sh1[h].z); qk[7] = f2b(sh1[h].w);
      *reinterpret_cast<bf16x8*>(&Ab[row][128 + scol]) = qk;
    }
    LGKM_BAR();  // b1: A staged

    // T14: issue NEXT tile's xe/hs loads now — they return during ph1/ph2
    {
      const size_t mn = ((size_t)blockIdx.x * PT + (it + 1 < PT ? it + 1 : it)) * 64;
      #pragma unroll
      for (int h = 0; h < 2; ++h) {
        const float* px = xe + (mn + srow + 32 * h) * 128 + scol;
        sx0[h] = *reinterpret_cast<const float4*>(px);
        sx1[h] = *reinterpret_cast<const float4*>(px + 4);
        const float* ph = hs + (mn + srow + 32 * h) * 128 + scol;
        sh0[h] = *reinterpret_cast<const float4*>(ph);
        sh1[h] = *reinterpret_cast<const float4*>(ph + 4);
      }
    }

    // eps for this tile (4 row-tiles)
    float ev[4][4];
    #pragma unroll
    for (int mt = 0; mt < 4; ++mt)
      #pragma unroll
      for (int r = 0; r < 4; ++r)
        ev[mt][r] = eps[(m0 + mt * 16 + lg * 4 + r) * 128 + n2];

    // ph1: t = relu(A@w1^T+b1)*sigm(A@w2^T+b2), wave w -> cols w*32+j*16+lr
    bf16x8 wf2[2][8];
    #pragma unroll
    for (int j = 0; j < 2; ++j) {
      const int n = w * 32 + j * 16 + lr;
      #pragma unroll
      for (int kt = 0; kt < 8; ++kt)
        wf2[j][kt] = *reinterpret_cast<const bf16x8*>(pw2v + (size_t)n * 256 + kt * 32 + lg * 8);
    }
    f32x4 ac1[2][4], ac2[2][4];   // [j][mt], mt = 4 row-tiles (64 rows)
    #pragma unroll
    for (int j = 0; j < 2; ++j)
      #pragma unroll
      for (int mt = 0; mt < 4; ++mt) { ac1[j][mt] = (f32x4){0.f,0.f,0.f,0.f}; ac2[j][mt] = (f32x4){0.f,0.f,0.f,0.f}; }
    #pragma unroll
    for (int kt = 0; kt < 8; ++kt) {
      bf16x8 af[4];
      #pragma unroll
      for (int mt = 0; mt < 4; ++mt)
        af[mt] = *reinterpret_cast<const bf16x8*>(&Ab[mt * 16 + lr][kt * 32 + lg * 8]);
      #pragma unroll
      for (int j = 0; j < 2; ++j)
        #pragma unroll
        for (int mt = 0; mt < 4; ++mt) {
          ac1[j][mt] = __builtin_amdgcn_mfma_f32_16x16x32_bf16(af[mt], wf1[j][kt], ac1[j][mt], 0, 0, 0);
          ac2[j][mt] = __builtin_amdgcn_mfma_f32_16x16x32_bf16(af[mt], wf2[j][kt], ac2[j][mt], 0, 0, 0);
        }
    }

    // stream ph2 weights while ph1 finishes
    bf16x8 wm[8], wl[8];
    #pragma unroll
    for (int kt = 0; kt < 8; ++kt) {
      wm[kt] = *reinterpret_cast<const bf16x8*>(pwmv + (size_t)n2 * 256 + kt * 32 + lg * 8);
      wl[kt] = *reinterpret_cast<const bf16x8*>(pwlv + (size_t)n2 * 256 + kt * 32 + lg * 8);
    }
    LGKM_BAR();  // b2: all A reads done; t may overlay Ab

    #pragma unroll
    for (int j = 0; j < 2; ++j)
      #pragma unroll
      for (int mt = 0; mt < 4; ++mt)
        #pragma unroll
        for (int r = 0; r < 4; ++r) {
          float t1 = ac1[j][mt][r] + bb1[j]; t1 = t1 > 0.f ? t1 : 0.f;
          float t2 = sigm(ac2[j][mt][r] + bb2[j]);
          Ab[mt * 16 + lg * 4 + r][w * 32 + j * 16 + lr] = f2b(t1 * t2);  // rows<64, cols<256: in-bounds
        }
    LGKM_BAR();  // b3: t ready

    // ph2: mu/ls = t @ {wmu,wls}^T + reparam sample
    f32x4 amc[4], alc[4];
    #pragma unroll
    for (int mt = 0; mt < 4; ++mt) { amc[mt] = (f32x4){0.f,0.f,0.f,0.f}; alc[mt] = (f32x4){0.f,0.f,0.f,0.f}; }
    #pragma unroll
    for (int kt = 0; kt < 8; ++kt) {
      #pragma unroll
      for (int mt = 0; mt < 4; ++mt) {
        bf16x8 at = *reinterpret_cast<const bf16x8*>(&Ab[mt * 16 + lr][kt * 32 + lg * 8]);
        amc[mt] = __builtin_amdgcn_mfma_f32_16x16x32_bf16(at, wm[kt], amc[mt], 0, 0, 0);
        alc[mt] = __builtin_amdgcn_mfma_f32_16x16x32_bf16(at, wl[kt], alc[mt], 0, 0, 0);
      }
    }
    #pragma unroll
    for (int mt = 0; mt < 4; ++mt)
      #pragma unroll
      for (int r = 0; r < 4; ++r) {
        size_t off = (m0 + mt * 16 + lg * 4 + r) * 128 + n2;
        float m_ = amc[mt][r] + bbm;
        float l_ = alc[mt][r] + bbl;
        mu[off] = m_;
        ls[off] = l_;
        samp[off] = m_ + exp2f_(1.44269504f * l_) * ev[mt][r];
      }
    LGKM_BAR();  // b4: t consumed before next tile's stage overwrites
  }
}

// ---------------------------------------------------------------------------
extern "C" void kernel_launch(void* const* d_in, const int* in_sizes, int n_in,
                              void* d_out, int out_size, void* d_ws, size_t ws_size,
                              hipStream_t stream) {
  const float* ext   = (const float*)d_in[0];
  const float* obs   = (const float*)d_in[1];
  const float* eps   = (const float*)d_in[2];
  const float* u_w1  = (const float*)d_in[3];
  const float* u_b1  = (const float*)d_in[4];
  const float* u_w2  = (const float*)d_in[5];
  const float* u_b2  = (const float*)d_in[6];
  const float* x_w1  = (const float*)d_in[7];
  const float* x_b1  = (const float*)d_in[8];
  const float* x_w2  = (const float*)d_in[9];
  const float* x_b2  = (const float*)d_in[10];
  const float* pw1   = (const float*)d_in[11];
  const float* pb1   = (const float*)d_in[12];
  const float* pw2   = (const float*)d_in[13];
  const float* pb2   = (const float*)d_in[14];
  const float* pwmu  = (const float*)d_in[15];
  const float* pbmu  = (const float*)d_in[16];
  const float* pwls  = (const float*)d_in[17];
  const float* pbls  = (const float*)d_in[18];
  const float* g_wih = (const float*)d_in[19];
  const float* g_whh = (const float*)d_in[20];
  const float* g_bih = (const float*)d_in[21];
  const float* g_bhh = (const float*)d_in[22];

  float* out = (float*)d_out;
  float* o_mu = out;
  float* o_ls = out + 16777216;
  float* o_sp = out + 33554432;
  float* o_hs = out + 50331648;
  float* o_xe = out + 67108864;
  // bf16 x_gates scratch (L*B*384 shorts = 100 MB) lives at the start of the
  // output region; fully consumed by k_grux before k_post overwrites it.
  short* gates = (short*)out;

  short* wb = (short*)d_ws;
  short* c_uw1  = wb + 0;
  short* c_uw2  = wb + 8192;
  short* c_xw1  = wb + 24576;
  short* c_xw2  = wb + 40960;
  short* c_wih  = wb + 57344;
  short* c_whh  = wb + 106496;
  short* c_pw1  = wb + 155648;
  short* c_pw2  = wb + 221184;
  short* c_pwmu = wb + 286720;
  short* c_pwls = wb + 319488;

  k_cvt<<<1376, 256, 0, stream>>>(u_w1, u_w2, x_w1, x_w2, g_wih, g_whh,
                                  pw1, pw2, pwmu, pwls, wb);
  k_upath<<<512, 512, 0, stream>>>(ext, c_uw1, u_b1, c_uw2, u_b2, c_wih, g_bih, g_bhh, gates);
  k_grux<<<640, 512, 0, stream>>>(gates, c_whh, g_bhh, o_hs,
                                  obs, c_xw1, x_b1, c_xw2, x_b2, o_xe);
  k_post<<<512, 512, 0, stream>>>(o_xe, o_hs, eps, c_pw1, pb1, c_pw2, pb2,
                                  c_pwmu, pbmu, c_pwls, pbls, o_mu, o_ls, o_sp);
}